// Round 2
// baseline (529.003 us; speedup 1.0000x reference)
//
#include <hip/hip_runtime.h>
#include <hip/hip_bf16.h>
#include <cstdint>

#define SDIM 200
#define HDIM 128
#define IDIM 4
#define BDIM 1024
#define LDK 72      // bf16 staging leading dim per 64-wide K-half (144 B rows)
#define LDEF 132    // fp32 epilogue leading dim (528 B rows)

typedef __attribute__((ext_vector_type(8))) short short8;
typedef __attribute__((ext_vector_type(4))) float f32x4;

__device__ __forceinline__ ushort f32_to_bf16u(float f) {
    uint32_t u = __builtin_bit_cast(uint32_t, f);
    u += 0x7FFFu + ((u >> 16) & 1u);   // RNE
    return (ushort)(u >> 16);
}
__device__ __forceinline__ float bf16u_to_f32(ushort h) {
    uint32_t u = ((uint32_t)h) << 16;
    return __builtin_bit_cast(float, u);
}
__device__ __forceinline__ void split8(const float* p, uint4* hi, uint4* lo) {
    union { ushort u[8]; uint4 v; } xh, xl;
    #pragma unroll
    for (int j = 0; j < 8; ++j) {
        float f = p[j];
        ushort h = f32_to_bf16u(f);
        float r = f - bf16u_to_f32(h);
        xh.u[j] = h;
        xl.u[j] = f32_to_bf16u(r);
    }
    *hi = xh.v; *lo = xl.v;
}

// ---------------------------------------------------------------------------
// Kernel 1 (R5): ii-merged hat GEMM. Grid = nbt x SDIM (bt-major: blk = bt*200+s
// -> XCD = s%8, same-s blocks share w tiles in one XCD's L2).
// A fragments (item, split bf16 hi/lo) loaded DIRECTLY global->regs once and
// persist across the ii loop (128 VGPRs) -> item HBM reads and item split VALU
// both /4 vs the (s,ii,bt) grid. W staged per-ii via proven LDS split path.
// ---------------------------------------------------------------------------
__global__ __launch_bounds__(256, 2) void hat_gemm(const float* __restrict__ item,
                                                   const float* __restrict__ w,
                                                   float* __restrict__ hat,
                                                   int b0, int nbt) {
    __shared__ ushort lds[4 * 128 * LDK];     // 73,728 B: Wh0|Wl0|Wh1|Wl1
    ushort* Wh0 = lds;
    ushort* Wl0 = lds + 128 * LDK;
    ushort* Wh1 = lds + 2 * 128 * LDK;
    ushort* Wl1 = lds + 3 * 128 * LDK;
    float*  ef  = (float*)lds;                // 128x132 fp32 = 67,584 B aliased

    const int blk = blockIdx.x;
    const int bt = blk / SDIM;                // bt-major ordering
    const int s  = blk % SDIM;
    const int t  = threadIdx.x;

    const int wave = t >> 6, lane = t & 63;
    const int wm = wave >> 1, wn = wave & 1;
    const int m0 = lane & 15, q = lane >> 4;

    // ---- A fragments: direct global->reg load + split, resident across ii ----
    short8 ah[2][2][4], al[2][2][4];
    {
        const float* ib = item +
            ((size_t)(b0 + bt * 128 + wm * 64 + m0) * SDIM + s) * HDIM;
        #pragma unroll
        for (int tm = 0; tm < 4; ++tm) {
            const float* p = ib + (size_t)(tm * 16) * SDIM * HDIM;
            #pragma unroll
            for (int st = 0; st < 2; ++st)
                #pragma unroll
                for (int kk = 0; kk < 2; ++kk) {
                    uint4 hi, lo;
                    split8(p + st * 64 + kk * 32 + q * 8, &hi, &lo);
                    ah[st][kk][tm] = __builtin_bit_cast(short8, hi);
                    al[st][kk][tm] = __builtin_bit_cast(short8, lo);
                }
        }
    }

    const float* wRow = w + (size_t)s * (IDIM * HDIM) * HDIM;

    #pragma unroll 1
    for (int ii = 0; ii < IDIM; ++ii) {
        if (ii) __syncthreads();              // ef readers done before W overwrite
        const float* wB = wRow + (size_t)ii * HDIM * HDIM;

        // ---- stage W (both 64-wide K-halves), split bf16 hi/lo ----
        #pragma unroll
        for (int c = t; c < 2048; c += 256) {
            int row = c >> 4, g = c & 15;
            int st = g >> 3, go = g & 7;
            uint4 hi, lo;
            split8(wB + (size_t)row * HDIM + st * 64 + go * 8, &hi, &lo);
            ushort* WH = st ? Wh1 : Wh0;
            ushort* WL = st ? Wl1 : Wl0;
            *(uint4*)(&WH[row * LDK + go * 8]) = hi;
            *(uint4*)(&WL[row * LDK + go * 8]) = lo;
        }
        __syncthreads();

        // ---- MFMA: 3-stream split-bf16, A from registers ----
        f32x4 acc[4][4];
        #pragma unroll
        for (int tm = 0; tm < 4; ++tm)
            #pragma unroll
            for (int tn = 0; tn < 4; ++tn)
                acc[tm][tn] = (f32x4){0.f, 0.f, 0.f, 0.f};

        #pragma unroll
        for (int st = 0; st < 2; ++st) {
            const ushort* WH = st ? Wh1 : Wh0;
            const ushort* WL = st ? Wl1 : Wl0;
            #pragma unroll
            for (int kk = 0; kk < 2; ++kk) {
                const int kof = kk * 32 + q * 8;
                short8 bh[4], bl[4];
                #pragma unroll
                for (int tn = 0; tn < 4; ++tn) {
                    int ro = (wn * 64 + tn * 16 + m0) * LDK + kof;
                    bh[tn] = *(const short8*)(&WH[ro]);
                    bl[tn] = *(const short8*)(&WL[ro]);
                }
                #pragma unroll
                for (int tm = 0; tm < 4; ++tm)
                    #pragma unroll
                    for (int tn = 0; tn < 4; ++tn) {
                        acc[tm][tn] = __builtin_amdgcn_mfma_f32_16x16x32_bf16(
                            ah[st][kk][tm], bl[tn], acc[tm][tn], 0, 0, 0);
                        acc[tm][tn] = __builtin_amdgcn_mfma_f32_16x16x32_bf16(
                            al[st][kk][tm], bh[tn], acc[tm][tn], 0, 0, 0);
                        acc[tm][tn] = __builtin_amdgcn_mfma_f32_16x16x32_bf16(
                            ah[st][kk][tm], bh[tn], acc[tm][tn], 0, 0, 0);
                    }
            }
        }
        __syncthreads();                      // W reads done before ef overwrite

        // ---- epilogue: acc -> ef (LDS transpose) -> coalesced float4 store ----
        #pragma unroll
        for (int tm = 0; tm < 4; ++tm) {
            #pragma unroll
            for (int tn = 0; tn < 4; ++tn) {
                int col = wn * 64 + tn * 16 + m0;
                #pragma unroll
                for (int rg = 0; rg < 4; ++rg) {
                    int row = wm * 64 + tm * 16 + q * 4 + rg;
                    ef[row * LDEF + col] = acc[tm][tn][rg];
                }
            }
        }
        __syncthreads();
        #pragma unroll
        for (int c = t; c < 4096; c += 256) {
            int row = c >> 5, cc = c & 31;
            int bl_ = bt * 128 + row;
            float4 v = *(const float4*)(&ef[row * LDEF + cc * 4]);
            *(float4*)(hat + (((size_t)bl_ * IDIM + ii) * SDIM + s) * HDIM + cc * 4) = v;
        }
    }
}

// ---------------------------------------------------------------------------
// Kernel 2 (v4, unchanged/proven): register-resident tile routing.
// ---------------------------------------------------------------------------
__global__ __launch_bounds__(256, 3) void routing4(const float* __restrict__ hat,
                                                   const int* __restrict__ mask,
                                                   float* __restrict__ out, int b0) {
    __shared__ float cw[SDIM];
    __shared__ float eall[SDIM];
    __shared__ float ew[SDIM];
    __shared__ float icp[8 * HDIM];
    __shared__ float ic[HDIM];
    __shared__ float icf[HDIM];
    __shared__ int   mk[SDIM];

    const int blk = blockIdx.x;
    const int bl = blk >> 2, ii = blk & 3;
    const int b = b0 + bl;
    const int t = threadIdx.x, lane = t & 63, wv = t >> 6;
    const int hq = (t & 31) * 4;
    const int sg = t >> 5;
    const float* base = hat + ((size_t)bl * IDIM + ii) * (SDIM * HDIM);

    if (t < SDIM) mk[t] = mask[(size_t)b * SDIM + t];

    float4 pf[25];
    #pragma unroll
    for (int j = 0; j < 25; ++j)
        pf[j] = *(const float4*)(base + (size_t)(sg + 8 * j) * HDIM + hq);
    __syncthreads();

    // ---- pass 0: uniform sw = 1/200, masked numerator
    {
        float4 u = {0.f, 0.f, 0.f, 0.f};
        #pragma unroll
        for (int j = 0; j < 25; ++j) {
            if (mk[sg + 8 * j]) {
                u.x += pf[j].x; u.y += pf[j].y; u.z += pf[j].z; u.w += pf[j].w;
            }
        }
        *(float4*)(&icp[sg * HDIM + hq]) = u;
    }
    __syncthreads();
    if (t < HDIM) {
        float v = 0.f;
        #pragma unroll
        for (int g = 0; g < 8; ++g) v += icp[g * HDIM + t];
        ic[t] = v * (1.0f / 200.0f);
    }
    __syncthreads();
    if (wv == 0) {
        float i0 = ic[lane], i1 = ic[lane + 64];
        float p = i0 * i0 + i1 * i1;
        #pragma unroll
        for (int off = 32; off > 0; off >>= 1) p += __shfl_xor(p, off);
        float fac = p / (1.0f + p) / sqrtf(p + 1e-9f);
        icf[lane] = i0 * fac;
        icf[lane + 64] = i1 * fac;
    }
    __syncthreads();

    for (int iter = 1; iter <= 2; ++iter) {
        float4 c4 = *(const float4*)(&icf[hq]);
        #pragma unroll
        for (int j = 0; j < 25; ++j) {
            float d = fmaf(pf[j].x, c4.x, fmaf(pf[j].y, c4.y,
                      fmaf(pf[j].z, c4.z, pf[j].w * c4.w)));
            d += __shfl_xor(d, 16);
            d += __shfl_xor(d, 8);
            d += __shfl_xor(d, 4);
            d += __shfl_xor(d, 2);
            d += __shfl_xor(d, 1);
            if ((t & 31) == 0) {
                int s = sg + 8 * j;
                cw[s] = (iter == 1) ? d : cw[s] + d;
            }
        }
        __syncthreads();

        float m = fmaxf(cw[lane], fmaxf(cw[lane + 64], cw[lane + 128]));
        if (lane < SDIM - 192) m = fmaxf(m, cw[lane + 192]);
        #pragma unroll
        for (int off = 32; off > 0; off >>= 1) m = fmaxf(m, __shfl_xor(m, off));
        if (t < SDIM) {
            float e = __expf(cw[t] - m);
            eall[t] = e;
            ew[t] = mk[t] ? e : 0.0f;
        }
        __syncthreads();

        float D = eall[lane] + eall[lane + 64] + eall[lane + 128]
                + ((lane < SDIM - 192) ? eall[lane + 192] : 0.0f);
        #pragma unroll
        for (int off = 32; off > 0; off >>= 1) D += __shfl_xor(D, off);

        {
            float4 u = {0.f, 0.f, 0.f, 0.f};
            #pragma unroll
            for (int j = 0; j < 25; ++j) {
                float wgt = ew[sg + 8 * j];
                u.x = fmaf(wgt, pf[j].x, u.x);
                u.y = fmaf(wgt, pf[j].y, u.y);
                u.z = fmaf(wgt, pf[j].z, u.z);
                u.w = fmaf(wgt, pf[j].w, u.w);
            }
            *(float4*)(&icp[sg * HDIM + hq]) = u;
        }
        __syncthreads();

        if (t < HDIM) {
            float v = 0.f;
            #pragma unroll
            for (int g = 0; g < 8; ++g) v += icp[g * HDIM + t];
            ic[t] = v / D;
        }
        __syncthreads();

        if (wv == 0) {
            float i0 = ic[lane], i1 = ic[lane + 64];
            float p = i0 * i0 + i1 * i1;
            #pragma unroll
            for (int off = 32; off > 0; off >>= 1) p += __shfl_xor(p, off);
            float fac = p / (1.0f + p) / sqrtf(p + 1e-9f);
            if (iter == 1) {
                icf[lane] = i0 * fac;
                icf[lane + 64] = i1 * fac;
            } else {
                out[((size_t)b * IDIM + ii) * HDIM + lane]      = i0 * fac;
                out[((size_t)b * IDIM + ii) * HDIM + lane + 64] = i1 * fac;
            }
        }
        if (iter == 1) __syncthreads();
    }
}

extern "C" void kernel_launch(void* const* d_in, const int* in_sizes, int n_in,
                              void* d_out, int out_size, void* d_ws, size_t ws_size,
                              hipStream_t stream) {
    const float* item = nullptr;
    const int*   msk  = nullptr;
    const float* w    = nullptr;
    for (int i = 0; i < n_in; ++i) {
        if (in_sizes[i] == BDIM * SDIM * HDIM)             item = (const float*)d_in[i];
        else if (in_sizes[i] == BDIM * SDIM)               msk  = (const int*)d_in[i];
        else if (in_sizes[i] == SDIM * IDIM * HDIM * HDIM) w    = (const float*)d_in[i];
    }
    if (!item) item = (const float*)d_in[0];
    if (!msk)  msk  = (const int*)d_in[1];
    if (!w)    w    = (const float*)d_in[2];

    float* hat = (float*)d_ws;                 // (chunk,I,S,H) fp32 workspace
    float* out = (float*)d_out;

    // Chunk at 512 batches: hat slice = 210 MB -> Infinity-Cache-resident
    // between producer (hat_gemm) and consumer (routing4) launches.
    const size_t perB = (size_t)IDIM * SDIM * HDIM * sizeof(float);
    size_t hatCap = ws_size / perB;
    int chunk = 512;
    if (hatCap < (size_t)chunk) chunk = (int)((hatCap / 128) * 128);
    if (chunk < 128) chunk = 128;
    for (int bb = 0; bb < BDIM; bb += chunk) {
        int cb = (BDIM - bb < chunk) ? (BDIM - bb) : chunk;
        int nbt = cb / 128;
        hat_gemm<<<nbt * SDIM, 256, 0, stream>>>(item, w, hat, bb, nbt);
        routing4<<<cb * IDIM, 256, 0, stream>>>(hat, msk, out, bb);
    }
}